// Round 1
// baseline (205.052 us; speedup 1.0000x reference)
//
#include <hip/hip_runtime.h>

// Problem constants (from reference)
constexpr int B_  = 16;
constexpr int NV_ = 10475;
constexpr int F_  = 20908;
constexpr int MAXC_ = 8;
constexpr int P_  = F_ * MAXC_;          // 167264 pairs per batch
constexpr float LINEAR_MAX_ = 1000.0f;

__global__ __launch_bounds__(256) void pen_distance_kernel(
    const float* __restrict__ v,        // (B, NV, 3) f32
    const int*   __restrict__ faces,    // (F, 3) i32
    const int2*  __restrict__ coll,     // (B, P) pairs (i32 x 2)
    float*       __restrict__ out)      // (B,)
{
    const int b = blockIdx.y;
    const int p = blockIdx.x * blockDim.x + threadIdx.x;

    float psi2 = 0.0f;

    if (p < P_) {
        const int2 pr = coll[(size_t)b * P_ + p];
        // valid iff both indices >= 0  <=>  sign bit of (x|y) clear
        if ((pr.x | pr.y) >= 0) {
            const float* __restrict__ vb = v + (size_t)b * (NV_ * 3);

            // ---- receiver triangle (idx 1) ----
            const int fr = pr.y * 3;
            const int r0i = faces[fr + 0] * 3;
            const int r1i = faces[fr + 1] * 3;
            const int r2i = faces[fr + 2] * 3;
            const float r0x = vb[r0i + 0], r0y = vb[r0i + 1], r0z = vb[r0i + 2];
            const float r1x = vb[r1i + 0], r1y = vb[r1i + 1], r1z = vb[r1i + 2];
            const float r2x = vb[r2i + 0], r2y = vb[r2i + 1], r2z = vb[r2i + 2];

            // centroid
            const float third = 1.0f / 3.0f;
            const float cx = (r0x + r1x + r2x) * third;
            const float cy = (r0y + r1y + r2y) * third;
            const float cz = (r0z + r1z + r2z) * third;

            // normal = cross(r1 - r0, r2 - r0), normalized
            const float e1x = r1x - r0x, e1y = r1y - r0y, e1z = r1z - r0z;
            const float e2x = r2x - r0x, e2y = r2y - r0y, e2z = r2z - r0z;
            float nx = e1y * e2z - e1z * e2y;
            float ny = e1z * e2x - e1x * e2z;
            float nz = e1x * e2y - e1y * e2x;
            const float nrm = sqrtf(nx * nx + ny * ny + nz * nz);
            const float inv = 1.0f / (nrm + 1e-12f);
            nx *= inv; ny *= inv; nz *= inv;

            // ---- intruder triangle (idx 0) ----
            const int fi = pr.x * 3;
            const int a0i = faces[fi + 0] * 3;
            const int a1i = faces[fi + 1] * 3;
            const int a2i = faces[fi + 2] * 3;

            #pragma unroll
            for (int k = 0; k < 3; ++k) {
                const int ai = (k == 0) ? a0i : (k == 1) ? a1i : a2i;
                const float ux = vb[ai + 0] - cx;
                const float uy = vb[ai + 1] - cy;
                const float uz = vb[ai + 2] - cz;
                float t = -(ux * nx + uy * ny + uz * nz);
                t = fminf(fmaxf(t, 0.0f), LINEAR_MAX_);
                psi2 = fmaf(t, t, psi2);
            }
        }
    }

    // ---- reduction: wave64 shfl -> LDS across waves -> one atomic/block ----
    #pragma unroll
    for (int off = 32; off > 0; off >>= 1)
        psi2 += __shfl_down(psi2, off, 64);

    __shared__ float wsum[4];   // 256 threads = 4 waves
    const int lane = threadIdx.x & 63;
    const int wid  = threadIdx.x >> 6;
    if (lane == 0) wsum[wid] = psi2;
    __syncthreads();

    if (threadIdx.x == 0) {
        const float blocksum = wsum[0] + wsum[1] + wsum[2] + wsum[3];
        atomicAdd(&out[b], blocksum);
    }
}

extern "C" void kernel_launch(void* const* d_in, const int* in_sizes, int n_in,
                              void* d_out, int out_size, void* d_ws, size_t ws_size,
                              hipStream_t stream) {
    const float* v     = (const float*)d_in[0];
    const int*   faces = (const int*)d_in[1];
    const int2*  coll  = (const int2*)d_in[2];
    float* out = (float*)d_out;

    // Harness poisons d_out to 0xAA before every timed launch — zero it here.
    hipMemsetAsync(out, 0, out_size * sizeof(float), stream);

    dim3 block(256);
    dim3 grid((P_ + 255) / 256, B_);
    pen_distance_kernel<<<grid, block, 0, stream>>>(v, faces, coll, out);
}

// Round 3
// 99.931 us; speedup vs baseline: 2.0519x; 2.0519x over previous
//
#include <hip/hip_runtime.h>

// Problem constants (from reference)
constexpr int B_  = 16;
constexpr int NV_ = 10475;
constexpr int F_  = 20908;
constexpr int MAXC_ = 8;
constexpr int P_  = F_ * MAXC_;          // 167264 pairs per batch (= 8 * F_)
constexpr float LINEAR_MAX_ = 1000.0f;

// One thread handles 8 pairs: p, p+F, p+2F, ..., p+7F  (P_ == 8*F_ exactly).
// All loads branchless (clamped index + multiplicative mask) so the compiler
// can schedule 8 independent gather chains per thread.
__global__ __launch_bounds__(256) void pen_distance_kernel(
    const float* __restrict__ v,        // (B, NV, 3) f32
    const int*   __restrict__ faces,    // (F, 3) i32
    const int2*  __restrict__ coll,     // (B, P) pairs (i32 x 2)
    float*       __restrict__ out)      // (B,)
{
    const int b = blockIdx.y;
    const int p = blockIdx.x * blockDim.x + threadIdx.x;

    float psi2 = 0.0f;

    if (p < F_) {
        const float* __restrict__ vb = v + (size_t)b * (NV_ * 3);
        const int2*  __restrict__ cb = coll + (size_t)b * P_ + p;

        #pragma unroll
        for (int k = 0; k < 8; ++k) {
            const int2 pr = cb[k * F_];
            // valid iff both indices >= 0
            const float m = ((pr.x | pr.y) >= 0) ? 1.0f : 0.0f;
            const int fR = ((pr.y > 0) ? pr.y : 0) * 3;   // receiver face
            const int fI = ((pr.x > 0) ? pr.x : 0) * 3;   // intruder face

            const int r0i = faces[fR + 0] * 3;
            const int r1i = faces[fR + 1] * 3;
            const int r2i = faces[fR + 2] * 3;
            const int a0i = faces[fI + 0] * 3;
            const int a1i = faces[fI + 1] * 3;
            const int a2i = faces[fI + 2] * 3;

            const float r0x = vb[r0i + 0], r0y = vb[r0i + 1], r0z = vb[r0i + 2];
            const float r1x = vb[r1i + 0], r1y = vb[r1i + 1], r1z = vb[r1i + 2];
            const float r2x = vb[r2i + 0], r2y = vb[r2i + 1], r2z = vb[r2i + 2];

            // centroid
            const float third = 1.0f / 3.0f;
            const float cx = (r0x + r1x + r2x) * third;
            const float cy = (r0y + r1y + r2y) * third;
            const float cz = (r0z + r1z + r2z) * third;

            // normal = cross(r1 - r0, r2 - r0), normalized
            const float e1x = r1x - r0x, e1y = r1y - r0y, e1z = r1z - r0z;
            const float e2x = r2x - r0x, e2y = r2y - r0y, e2z = r2z - r0z;
            float nx = e1y * e2z - e1z * e2y;
            float ny = e1z * e2x - e1x * e2z;
            float nz = e1x * e2y - e1y * e2x;
            const float nrm = sqrtf(nx * nx + ny * ny + nz * nz);
            const float inv = 1.0f / (nrm + 1e-12f);
            nx *= inv; ny *= inv; nz *= inv;

            float s = 0.0f;
            {
                const float ux = vb[a0i + 0] - cx;
                const float uy = vb[a0i + 1] - cy;
                const float uz = vb[a0i + 2] - cz;
                float t = -(ux * nx + uy * ny + uz * nz);
                t = fminf(fmaxf(t, 0.0f), LINEAR_MAX_);
                s = fmaf(t, t, s);
            }
            {
                const float ux = vb[a1i + 0] - cx;
                const float uy = vb[a1i + 1] - cy;
                const float uz = vb[a1i + 2] - cz;
                float t = -(ux * nx + uy * ny + uz * nz);
                t = fminf(fmaxf(t, 0.0f), LINEAR_MAX_);
                s = fmaf(t, t, s);
            }
            {
                const float ux = vb[a2i + 0] - cx;
                const float uy = vb[a2i + 1] - cy;
                const float uz = vb[a2i + 2] - cz;
                float t = -(ux * nx + uy * ny + uz * nz);
                t = fminf(fmaxf(t, 0.0f), LINEAR_MAX_);
                s = fmaf(t, t, s);
            }

            psi2 = fmaf(m, s, psi2);
        }
    }

    // ---- reduction: wave64 shfl -> LDS across waves -> one atomic/block ----
    #pragma unroll
    for (int off = 32; off > 0; off >>= 1)
        psi2 += __shfl_down(psi2, off, 64);

    __shared__ float wsum[4];   // 256 threads = 4 waves
    const int lane = threadIdx.x & 63;
    const int wid  = threadIdx.x >> 6;
    if (lane == 0) wsum[wid] = psi2;
    __syncthreads();

    if (threadIdx.x == 0) {
        const float blocksum = wsum[0] + wsum[1] + wsum[2] + wsum[3];
        atomicAdd(&out[b], blocksum);
    }
}

extern "C" void kernel_launch(void* const* d_in, const int* in_sizes, int n_in,
                              void* d_out, int out_size, void* d_ws, size_t ws_size,
                              hipStream_t stream) {
    const float* v     = (const float*)d_in[0];
    const int*   faces = (const int*)d_in[1];
    const int2*  coll  = (const int2*)d_in[2];
    float* out = (float*)d_out;

    // Harness poisons d_out to 0xAA before every timed launch — zero it here.
    hipMemsetAsync(out, 0, out_size * sizeof(float), stream);

    dim3 block(256);
    dim3 grid((F_ + 255) / 256, B_);   // 82 x 16 blocks; each thread does 8 pairs
    pen_distance_kernel<<<grid, block, 0, stream>>>(v, faces, coll, out);
}